// Round 1
// baseline (5075.656 us; speedup 1.0000x reference)
//
#include <hip/hip_runtime.h>
#include <hip/hip_bf16.h>
#include <math.h>

// Problem constants
#define VOCAB 32000
#define DDIM  128
#define BATCH 4
#define SEQ   2048
#define NTOK  (BATCH * SEQ)      // 8192
#define N_INNER 4

typedef float v2f  __attribute__((ext_vector_type(2)));
typedef float f32x4 __attribute__((ext_vector_type(4)));
typedef __bf16 bf16x8 __attribute__((ext_vector_type(8)));

__device__ __forceinline__ unsigned short f2bf(float x) {
    unsigned int u = __float_as_uint(x);
    unsigned int r = u + 0x7fffu + ((u >> 16) & 1u);
    return (unsigned short)(r >> 16);
}

// ---------------------------------------------------------------------------
// K1: convert out_w fp32 [32000,128] -> bf16 (row-major, K contiguous)
// ---------------------------------------------------------------------------
__global__ void convert_w_kernel(const float* __restrict__ src,
                                 unsigned short* __restrict__ dst, int n4) {
    int i = blockIdx.x * blockDim.x + threadIdx.x;
    if (i < n4) {
        float4 v = ((const float4*)src)[i];
        ushort4 o;
        o.x = f2bf(v.x); o.y = f2bf(v.y); o.z = f2bf(v.z); o.w = f2bf(v.w);
        ((ushort4*)dst)[i] = o;
    }
}

// ---------------------------------------------------------------------------
// K2: per-token precompute:
//   tok            = embed_w[id]                          [128]
//   mod_all[n][j]  = sum_k tok[k] * mod_w[j,k]
//   tokg_all[n][j] = sum_k tok[k] * gate_w[j, 128+k] + gate_b[j]
// One block = 32 tokens; weight row register-resident per thread.
// ---------------------------------------------------------------------------
#define TPB_TOKENS 32
__global__ __launch_bounds__(256) void prep_kernel(
    const int* __restrict__ ids, const float* __restrict__ embed_w,
    const float* __restrict__ gate_w, const float* __restrict__ gate_b,
    const float* __restrict__ mod_w,
    float* __restrict__ mod_all, float* __restrict__ tokg_all) {

    __shared__ float tokL[TPB_TOKENS * 132];  // tok[tt][k] padded stride 132
    const int tid = threadIdx.x;
    const int n0 = blockIdx.x * TPB_TOKENS;

    // stage 32 tokens (gathered embeddings) into LDS
    for (int idx = tid; idx < TPB_TOKENS * DDIM; idx += 256) {
        int tt = idx >> 7, k = idx & 127;
        int id = ids[n0 + tt];
        tokL[tt * 132 + k] = embed_w[(size_t)id * DDIM + k];
    }

    // load this thread's fixed weight row into registers
    const bool is_mod = tid < DDIM;
    const int j = is_mod ? tid : tid - DDIM;
    const float* wrow = is_mod ? (mod_w + (size_t)j * DDIM)
                               : (gate_w + (size_t)j * 2 * DDIM + DDIM);
    float wr[DDIM];
#pragma unroll
    for (int q = 0; q < DDIM / 4; ++q) {
        float4 v = ((const float4*)wrow)[q];
        wr[4 * q + 0] = v.x; wr[4 * q + 1] = v.y;
        wr[4 * q + 2] = v.z; wr[4 * q + 3] = v.w;
    }
    const float bias = is_mod ? 0.0f : gate_b[j];
    float* outp = is_mod ? mod_all : tokg_all;

    __syncthreads();

    for (int tt = 0; tt < TPB_TOKENS; ++tt) {
        float acc = 0.0f;
        const float* tp = &tokL[tt * 132];
#pragma unroll
        for (int q = 0; q < DDIM / 4; ++q) {
            float4 tv = *(const float4*)(tp + 4 * q);
            acc = fmaf(wr[4 * q + 0], tv.x, acc);
            acc = fmaf(wr[4 * q + 1], tv.y, acc);
            acc = fmaf(wr[4 * q + 2], tv.z, acc);
            acc = fmaf(wr[4 * q + 3], tv.w, acc);
        }
        outp[(size_t)(n0 + tt) * DDIM + j] = acc + bias;
    }
}

// ---------------------------------------------------------------------------
// K3: sequential gated recurrence. One block per batch row (4 blocks).
// 512 threads: thread = j*4 + p ; j in [0,128) output index, p = k-chunk.
// Weights register-resident (32 fp32 of W-row + 32 of gate-row per thread).
// State broadcast via double-buffered LDS (chunk stride 40 floats: pad to
// spread the 4 chunk bases across bank quads).
// ---------------------------------------------------------------------------
__global__ __launch_bounds__(512, 2) void recur_kernel(
    const float* __restrict__ W, const float* __restrict__ gate_w,
    const float* __restrict__ mod_all, const float* __restrict__ tokg_all,
    unsigned short* __restrict__ states_bf16) {

    __shared__ float sbuf[2][160];  // 4 chunks of 32 floats, stride 40

    const int b = blockIdx.x;
    const int tid = threadIdx.x;
    const int j = tid >> 2;
    const int p = tid & 3;

    // register-resident weight chunks: W[j][p*32 .. +31], gate_w[j][p*32 .. +31]
    v2f wv[16], gv[16];
    {
        const v2f* wrow = (const v2f*)(W + (size_t)j * DDIM + p * 32);
        const v2f* grow = (const v2f*)(gate_w + (size_t)j * 2 * DDIM + p * 32);
#pragma unroll
        for (int q = 0; q < 16; ++q) { wv[q] = wrow[q]; gv[q] = grow[q]; }
    }

    if (p == 0) sbuf[0][(j >> 5) * 40 + (j & 31)] = 0.0f;
    float sj = 0.0f;

    const float* modp = mod_all  + (size_t)b * SEQ * DDIM + j;
    const float* tgp  = tokg_all + (size_t)b * SEQ * DDIM + j;
    float modv = modp[0];
    float tgv  = tgp[0];
    __syncthreads();

    int cur = 0;
    for (int t = 0; t < SEQ; ++t) {
        const int tn = (t < SEQ - 1) ? (t + 1) : t;
        const float modv_n = modp[(size_t)tn * DDIM];  // prefetch next token
        const float tgv_n  = tgp[(size_t)tn * DDIM];

#pragma unroll
        for (int it = 0; it < N_INNER; ++it) {
            const v2f* sp = (const v2f*)(&sbuf[cur][p * 40]);
            v2f aw0 = {0.f, 0.f}, aw1 = {0.f, 0.f};
            v2f ag0 = {0.f, 0.f}, ag1 = {0.f, 0.f};
#pragma unroll
            for (int q = 0; q < 16; q += 2) {
                v2f s0 = sp[q], s1 = sp[q + 1];
                aw0 = __builtin_elementwise_fma(wv[q],     s0, aw0);
                aw1 = __builtin_elementwise_fma(wv[q + 1], s1, aw1);
                ag0 = __builtin_elementwise_fma(gv[q],     s0, ag0);
                ag1 = __builtin_elementwise_fma(gv[q + 1], s1, ag1);
            }
            v2f aw = aw0 + aw1, ag = ag0 + ag1;
            float dw = aw.x + aw.y;
            float dg = ag.x + ag.y;
            dw += __shfl_xor(dw, 1); dw += __shfl_xor(dw, 2);
            dg += __shfl_xor(dg, 1); dg += __shfl_xor(dg, 2);

            const float pre = dw + modv;
            const float h = 0.5f * pre * (1.0f + erff(pre * 0.70710678118654752f));
            const float g = 1.0f / (1.0f + __expf(-(dg + tgv)));
            sj = sj + g * (h - sj);

            const int nxt = cur ^ 1;
            if (p == 0) sbuf[nxt][(j >> 5) * 40 + (j & 31)] = sj;
            __syncthreads();
            cur = nxt;
        }

        if (p == 0)
            states_bf16[(size_t)(b * SEQ + t) * DDIM + j] = f2bf(sj);
        modv = modv_n; tgv = tgv_n;
    }
}

// ---------------------------------------------------------------------------
// K4: logits GEMM: out[r][v] = sum_k states[r][k]*out_w[v][k] + out_b[v]
// M=8192, N=32000, K=128 (single K pass). bf16 MFMA 16x16x32, 128x128 tile,
// 4 waves in 2x2, fragments loaded straight from global (K-contiguous 16B).
// ---------------------------------------------------------------------------
__global__ __launch_bounds__(256) void logits_gemm_kernel(
    const unsigned short* __restrict__ A,   // states bf16 [8192][128]
    const unsigned short* __restrict__ Bw,  // out_w  bf16 [32000][128]
    const float* __restrict__ bias,         // [32000]
    float* __restrict__ out) {              // fp32 [8192][32000]

    const int nt = blockIdx.x;   // 0..249
    const int mt = blockIdx.y;   // 0..63
    const int wave = threadIdx.x >> 6;
    const int lane = threadIdx.x & 63;
    const int wm = (wave >> 1) * 64;
    const int wn = (wave & 1) * 64;
    const int l15 = lane & 15;
    const int kq = lane >> 4;    // 0..3

    f32x4 acc[4][4] = {};

#pragma unroll
    for (int kk = 0; kk < 4; ++kk) {
        bf16x8 af[4], bfr[4];
#pragma unroll
        for (int i = 0; i < 4; ++i) {
            const int row = mt * 128 + wm + i * 16 + l15;
            af[i] = *(const bf16x8*)(A + (size_t)row * DDIM + kk * 32 + kq * 8);
            const int col = nt * 128 + wn + i * 16 + l15;
            bfr[i] = *(const bf16x8*)(Bw + (size_t)col * DDIM + kk * 32 + kq * 8);
        }
#pragma unroll
        for (int mi = 0; mi < 4; ++mi)
#pragma unroll
            for (int ni = 0; ni < 4; ++ni)
                acc[mi][ni] = __builtin_amdgcn_mfma_f32_16x16x32_bf16(
                    af[mi], bfr[ni], acc[mi][ni], 0, 0, 0);
    }

#pragma unroll
    for (int ni = 0; ni < 4; ++ni) {
        const int col = nt * 128 + wn + ni * 16 + l15;
        const float bv = bias[col];
#pragma unroll
        for (int mi = 0; mi < 4; ++mi) {
            const int row0 = mt * 128 + wm + mi * 16 + kq * 4;
#pragma unroll
            for (int i = 0; i < 4; ++i) {
                out[(size_t)(row0 + i) * VOCAB + col] = acc[mi][ni][i] + bv;
            }
        }
    }
}

// ---------------------------------------------------------------------------
// launch
// ---------------------------------------------------------------------------
extern "C" void kernel_launch(void* const* d_in, const int* in_sizes, int n_in,
                              void* d_out, int out_size, void* d_ws, size_t ws_size,
                              hipStream_t stream) {
    const int*   ids      = (const int*)d_in[0];
    const float* embed_w  = (const float*)d_in[1];
    const float* W        = (const float*)d_in[2];
    const float* gate_w   = (const float*)d_in[3];
    const float* gate_b   = (const float*)d_in[4];
    const float* mod_w    = (const float*)d_in[5];
    const float* out_w    = (const float*)d_in[6];
    const float* out_b    = (const float*)d_in[7];
    float* out = (float*)d_out;

    char* ws = (char*)d_ws;
    float* mod_all            = (float*)(ws);                      // 4 MiB
    float* tokg_all           = (float*)(ws + 4194304);            // 4 MiB
    unsigned short* states    = (unsigned short*)(ws + 8388608);   // 2 MiB
    unsigned short* out_w_bf  = (unsigned short*)(ws + 10485760);  // 8 MiB

    // K1: out_w -> bf16
    {
        int n4 = VOCAB * DDIM / 4;  // 1,024,000
        convert_w_kernel<<<(n4 + 255) / 256, 256, 0, stream>>>(out_w, out_w_bf, n4);
    }
    // K2: per-token mod / tok_gate
    prep_kernel<<<NTOK / TPB_TOKENS, 256, 0, stream>>>(
        ids, embed_w, gate_w, gate_b, mod_w, mod_all, tokg_all);
    // K3: sequential recurrence (4 independent chains)
    recur_kernel<<<BATCH, 512, 0, stream>>>(W, gate_w, mod_all, tokg_all, states);
    // K4: logits projection
    {
        dim3 grid(VOCAB / 128, NTOK / 128);  // (250, 64)
        logits_gemm_kernel<<<grid, 256, 0, stream>>>(states, out_w_bf, out_b, out);
    }
}